// Round 5
// baseline (1017.228 us; speedup 1.0000x reference)
//
#include <hip/hip_runtime.h>

// GNN NNConv, N=25000, E=50000, C=49, 3 live layers (layer 3 of ref is dead code).
// msg[e,o] = sum_k t[e,k]*U_k[src,o] + U_b[src,o];  U per NODE (GEMM).
// U stored as U[n][o][4] (k innermost) -> per-edge gather is ONE float4/lane.
// Root GEMV hoisted into the dense kernels (Rt = h@root_w + cb, lanes 196..244).
// CSR gather: branchless 4-edge quads, 8 nodes/block for full occupancy.

#define N 25000
#define E 50000
#define C 49
#define C2 196
#define SLOPE 0.01f
#define BPN 32            // nodes per block in dense kernels
#define GK 2              // nodes per wave in gathpre
#define NPB 8             // nodes per block in gathpre

__device__ __forceinline__ float leaky(float v) { return v > 0.f ? v : SLOPE * v; }
#define RFL(x) __builtin_amdgcn_readfirstlane(x)

__global__ void deg_kernel(const int* __restrict__ ei, int* __restrict__ deg) {
    int e = blockIdx.x * 256 + threadIdx.x;
    if (e < E) atomicAdd(&deg[ei[E + e]], 1);
}

// exclusive prefix over deg -> rowptr[0..N]; 1024 threads, shfl-based (2 barriers)
__global__ __launch_bounds__(1024) void scan_kernel(const int* __restrict__ deg,
                                                    int* __restrict__ rowptr) {
    __shared__ int wsum[16];
    int t = threadIdx.x, lane = t & 63, wv = t >> 6;
    int base = t * 25;
    int loc[25];
    int run = 0;
#pragma unroll
    for (int i = 0; i < 25; i++) {
        loc[i] = run;
        int idx = base + i;
        run += (idx < N) ? deg[idx] : 0;
    }
    int inc = run;
#pragma unroll
    for (int s = 1; s < 64; s <<= 1) {
        int v = __shfl_up(inc, s, 64);
        if (lane >= s) inc += v;
    }
    if (lane == 63) wsum[wv] = inc;
    __syncthreads();
    if (t < 16) {
        int v = wsum[t];
#pragma unroll
        for (int s = 1; s < 16; s <<= 1) {
            int u = __shfl_up(v, s, 64);
            if (t >= s) v += u;
        }
        wsum[t] = v;
    }
    __syncthreads();
    int pbase = inc - run + (wv ? wsum[wv - 1] : 0);
#pragma unroll
    for (int i = 0; i < 25; i++) {
        int idx = base + i;
        if (idx <= N) rowptr[idx] = pbase + loc[i];
    }
}

// CSR scatter + edge-MLP: PK[l][pos] = {src_as_float, t0, t1, t2}
__global__ void scatter_kernel(const int* __restrict__ ei, const float* __restrict__ ea,
                               const float* __restrict__ w1, const float* __restrict__ b1,
                               const int* __restrict__ rowptr, int* __restrict__ cnt,
                               float* __restrict__ PK) {
    int e = blockIdx.x * 256 + threadIdx.x;
    if (e >= E) return;
    int s = ei[e], d = ei[E + e];
    int pos = rowptr[d] + atomicAdd(&cnt[d], 1);
    float a[10];
#pragma unroll
    for (int j = 0; j < 10; j++) a[j] = ea[e * 10 + j];
#pragma unroll
    for (int l = 0; l < 3; l++) {
        float tk[3];
#pragma unroll
        for (int k = 0; k < 3; k++) {
            float acc = b1[l * 3 + k];
#pragma unroll
            for (int j = 0; j < 10; j++) acc += a[j] * w1[l * 30 + j * 3 + k];
            tk[k] = fmaxf(acc, 0.f);
        }
        float4 rec = make_float4(__int_as_float(s), tk[0], tk[1], tk[2]);
        *reinterpret_cast<float4*>(PK + ((size_t)l * E + pos) * 4) = rec;
    }
}

// shared GEMM phase: hs[BPN][52] -> U[n][o*4+k] (t<196) and Rt[n][o]=h@rw+cb (t in [196,245))
__device__ __forceinline__ void gemm_phase(const float (*hs)[52], int base, int nv,
                                           const float* __restrict__ w2,
                                           const float* __restrict__ b2,
                                           const float* __restrict__ rw,
                                           const float* __restrict__ cb,
                                           float* __restrict__ U, float* __restrict__ Rt,
                                           int t) {
    if (t >= 245) return;
    int k = t / C, o = t % C;
    const float* Wp = (k < 3 ? w2 + k * (C * C) : (k == 3 ? b2 : rw)) + o;
    float bias = (k == 4) ? cb[o] : 0.f;
    float w[52];
#pragma unroll
    for (int i = 0; i < C; i++) w[i] = Wp[i * C];
    w[49] = w[50] = w[51] = 0.f;
#pragma unroll 2
    for (int n = 0; n < nv; n++) {
        float acc = bias;
#pragma unroll
        for (int i4 = 0; i4 < 13; i4++) {
            float4 hv = *reinterpret_cast<const float4*>(&hs[n][i4 * 4]);
            acc += hv.x * w[i4 * 4] + hv.y * w[i4 * 4 + 1] + hv.z * w[i4 * 4 + 2] +
                   hv.w * w[i4 * 4 + 3];
        }
        if (k < 4) U[(size_t)(base + n) * C2 + o * 4 + k] = acc;
        else Rt[(size_t)(base + n) * C + o] = acc;
    }
}

// fused: h = leaky(x@lin_w+lin_b) -> out(JK init) + hs; then U0, Rt0
__global__ __launch_bounds__(256) void h2u0_kernel(
    const float* __restrict__ x, const float* __restrict__ lw, const float* __restrict__ lb,
    const float* __restrict__ w2, const float* __restrict__ b2, const float* __restrict__ rw,
    const float* __restrict__ cb, float* __restrict__ out, float* __restrict__ U,
    float* __restrict__ Rt) {
    __shared__ float xs[BPN][56];
    __shared__ float hs[BPN][52];
    int t = threadIdx.x, base = blockIdx.x * BPN;
    int nv = min(BPN, N - base);
    for (int e = t; e < nv * 56; e += 256) xs[e / 56][e % 56] = x[(size_t)base * 56 + e];
    for (int j = t; j < BPN * 3; j += 256) hs[j / 3][C + (j % 3)] = 0.f;
    __syncthreads();
    int r = t >> 6, c = t & 63;
    if (c < C) {
        float w[56];
#pragma unroll
        for (int i = 0; i < 56; i++) w[i] = lw[i * C + c];
        float bias = lb[c];
        for (int n = r; n < nv; n += 4) {
            float acc = bias;
#pragma unroll
            for (int i4 = 0; i4 < 14; i4++) {
                float4 hv = *reinterpret_cast<const float4*>(&xs[n][i4 * 4]);
                acc += hv.x * w[i4 * 4] + hv.y * w[i4 * 4 + 1] + hv.z * w[i4 * 4 + 2] +
                       hv.w * w[i4 * 4 + 3];
            }
            acc = leaky(acc);
            out[(size_t)(base + n) * C + c] = acc;
            hs[n][c] = acc;
        }
    }
    __syncthreads();
    gemm_phase(hs, base, nv, w2, b2, rw, cb, U, Rt, t);
}

// BN(prev pre) -> JK out + hs; then U, Rt for this layer
__global__ __launch_bounds__(256) void uni_kernel(
    const float* __restrict__ in, const float* __restrict__ st, const float* __restrict__ w2,
    const float* __restrict__ b2, const float* __restrict__ rw, const float* __restrict__ cb,
    float* __restrict__ out, float* __restrict__ U, float* __restrict__ Rt) {
    __shared__ float hs[BPN][52];
    __shared__ float scl[52], sft[52];
    int t = threadIdx.x, base = blockIdx.x * BPN;
    int nv = min(BPN, N - base);
    if (t < C) { scl[t] = st[128 + t]; sft[t] = st[192 + t]; }
    for (int j = t; j < BPN * 3; j += 256) hs[j / 3][C + j % 3] = 0.f;
    __syncthreads();
    for (int e = t; e < nv * C; e += 256) {
        int n = e / C, i = e % C;
        float v = in[(size_t)base * C + e];
        v = leaky(v * scl[i] + sft[i]);
        out[(size_t)base * C + e] += v;
        hs[n][i] = v;
    }
    __syncthreads();
    gemm_phase(hs, base, nv, w2, b2, rw, cb, U, Rt, t);
}

// CSR gather (4-edge branchless quads) + Rt add => pre; stats; last block -> BN params
__global__ __launch_bounds__(256) void gathpre_kernel(
    const int* __restrict__ rowptr, const float* __restrict__ PK, const float* __restrict__ U,
    const float* __restrict__ Rt, const float* __restrict__ gm, const float* __restrict__ bt,
    float* __restrict__ pre, float* __restrict__ st, int nblocks) {
    __shared__ float red[8][64];
    __shared__ int lastf;
    int t = threadIdx.x, wv = t >> 6, c = t & 63;
    int n0 = blockIdx.x * NPB + wv * GK;
    float s = 0.f, q = 0.f;
    int nend = min(n0 + GK, N);
    const float4* PK4 = reinterpret_cast<const float4*>(PK);
    for (int n = n0; n < nend; n++) {
        int nu = RFL(n);
        int j0 = RFL(rowptr[nu]);
        int j1 = RFL(rowptr[nu + 1]);
        if (c < C) {
            float rr = Rt[(size_t)nu * C + c];
            float a0 = 0.f, a1 = 0.f, a2 = 0.f, a3 = 0.f;
            int jc = max(j1 - 1, j0);  // clamp target (d=0 safe)
            int j = j0;
            do {
#define EDGE_TERM(K, AK)                                                          \
                {                                                                 \
                    int jj = min(j + K, jc);                                      \
                    float4 m = PK4[jj];                                           \
                    int sidx = RFL(__float_as_int(m.x));                          \
                    sidx = min(max(sidx, 0), N - 1);                              \
                    float4 u = *reinterpret_cast<const float4*>(                  \
                        U + (size_t)sidx * C2 + c * 4);                           \
                    float sc = (j + K < j1) ? 1.f : 0.f;                          \
                    AK += sc * (m.y * u.x + m.z * u.y + m.w * u.z + u.w);         \
                }
                EDGE_TERM(0, a0)
                EDGE_TERM(1, a1)
                EDGE_TERM(2, a2)
                EDGE_TERM(3, a3)
#undef EDGE_TERM
                j += 4;
            } while (j < j1);
            float inv = 1.0f / fmaxf((float)(j1 - j0), 1.0f);
            float acc = (a0 + a1 + a2 + a3) * inv + rr;
            pre[(size_t)nu * C + c] = acc;
            s += acc;
            q += acc * acc;
        }
    }
    red[wv][c] = s;
    red[4 + wv][c] = q;
    __syncthreads();
    if (t < C) {
        float S = red[0][t] + red[1][t] + red[2][t] + red[3][t];
        float Q = red[4][t] + red[5][t] + red[6][t] + red[7][t];
        atomicAdd(&st[t], S);
        atomicAdd(&st[64 + t], Q);
    }
    __threadfence();
    if (t == 0) lastf = (atomicAdd((int*)(st + 250), 1) == nblocks - 1) ? 1 : 0;
    __syncthreads();
    if (lastf && t < C) {
        float S = atomicAdd(&st[t], 0.0f);
        float Q = atomicAdd(&st[64 + t], 0.0f);
        float mu = S * (1.0f / N);
        float var = Q * (1.0f / N) - mu * mu;
        float sc = rsqrtf(var + 1e-5f) * gm[t];
        st[128 + t] = sc;
        st[192 + t] = bt[t] - mu * sc;
    }
}

// last layer: out += leaky(pre*sc+sh)
__global__ void fnorm_kernel(const float* __restrict__ pre, const float* __restrict__ st,
                             float* __restrict__ out) {
    int idx = blockIdx.x * 256 + threadIdx.x;
    if (idx >= N * C) return;
    int c = idx % C;
    out[idx] += leaky(pre[idx] * st[128 + c] + st[192 + c]);
}

extern "C" void kernel_launch(void* const* d_in, const int* in_sizes, int n_in,
                              void* d_out, int out_size, void* d_ws, size_t ws_size,
                              hipStream_t stream) {
    const float* x  = (const float*)d_in[0];
    const int* ei   = (const int*)d_in[1];
    const float* ea = (const float*)d_in[2];
    const float* lw = (const float*)d_in[3];
    const float* lb = (const float*)d_in[4];
    const float* w1 = (const float*)d_in[5];
    const float* b1 = (const float*)d_in[6];
    const float* w2 = (const float*)d_in[7];
    const float* b2 = (const float*)d_in[8];
    const float* rw = (const float*)d_in[9];
    const float* cb = (const float*)d_in[10];
    const float* gm = (const float*)d_in[11];
    const float* bt = (const float*)d_in[12];
    float* out = (float*)d_out;

    float* ws     = (float*)d_ws;
    int*   deg    = (int*)ws;                 // N
    int*   cnt    = deg + N;                  // N
    float* st     = (float*)(cnt + N);        // 768 (layer l at st+256*l; ctr at +250)
    int*   rowptr = (int*)(st + 768);         // N+1
    float* PK     = (float*)(rowptr + N + 1); // 3*E*4
    float* agg    = PK + (size_t)12 * E;      // N*C (pre)
    float* Rt     = agg + (size_t)N * C;      // N*C
    float* U      = Rt + (size_t)N * C;       // N*C2

    hipMemsetAsync(deg, 0, (size_t)(2 * N + 768) * sizeof(int), stream);
    deg_kernel<<<(E + 255) / 256, 256, 0, stream>>>(ei, deg);
    scan_kernel<<<1, 1024, 0, stream>>>(deg, rowptr);
    scatter_kernel<<<(E + 255) / 256, 256, 0, stream>>>(ei, ea, w1, b1, rowptr, cnt, PK);
    h2u0_kernel<<<(N + BPN - 1) / BPN, 256, 0, stream>>>(x, lw, lb, w2, b2, rw, cb, out, U, Rt);

    const int GPB = (N + NPB - 1) / NPB;
    for (int l = 0; l < 3; l++) {
        if (l > 0) {
            uni_kernel<<<(N + BPN - 1) / BPN, 256, 0, stream>>>(
                agg, st + (l - 1) * 256, w2 + (size_t)l * 3 * C * C, b2 + (size_t)l * C * C,
                rw + (size_t)l * C * C, cb + l * C, out, U, Rt);
        }
        gathpre_kernel<<<GPB, 256, 0, stream>>>(
            rowptr, PK + (size_t)l * E * 4, U, Rt, gm + l * C, bt + l * C,
            agg, st + l * 256, GPB);
    }
    fnorm_kernel<<<(N * C + 255) / 256, 256, 0, stream>>>(agg, st + 2 * 256, out);
}

// Round 6
// 240.248 us; speedup vs baseline: 4.2341x; 4.2341x over previous
//
#include <hip/hip_runtime.h>

// GNN NNConv, N=25000, E=50000, C=49, 3 live layers (layer 3 of ref is dead code).
// msg[e,o] = sum_k t[e,k]*U_k[src,o] + U_b[src,o];  U per NODE (GEMM).
// U stored as U[n][o][4] (k innermost) -> per-edge gather is ONE float4/lane.
// Root GEMV hoisted into dense kernels (Rt = h@root_w + cb, lanes 196..244).
// BN stats: per-block atomicAdd into 8 replicated slots (NO __threadfence — a
// last-block-finalize fence protocol cost 90ns/block = 282us at 3125 blocks).
// BN finalize recomputed cheaply by each consumer block from raw S/Q.

#define N 25000
#define E 50000
#define C 49
#define C2 196
#define SLOPE 0.01f
#define BPN 32            // nodes per block in dense kernels
#define GK 2              // nodes per wave in gathpre
#define NPB 8             // nodes per block in gathpre
#define NREP 8            // stat replicas (layer stride 1024 floats, replica stride 128)

__device__ __forceinline__ float leaky(float v) { return v > 0.f ? v : SLOPE * v; }
#define RFL(x) __builtin_amdgcn_readfirstlane(x)

__global__ void deg_kernel(const int* __restrict__ ei, int* __restrict__ deg) {
    int e = blockIdx.x * 256 + threadIdx.x;
    if (e < E) atomicAdd(&deg[ei[E + e]], 1);
}

// exclusive prefix over deg -> rowptr[0..N]; 1024 threads, shfl-based
__global__ __launch_bounds__(1024) void scan_kernel(const int* __restrict__ deg,
                                                    int* __restrict__ rowptr) {
    __shared__ int wsum[16];
    int t = threadIdx.x, lane = t & 63, wv = t >> 6;
    int base = t * 25;
    int loc[25];
    int run = 0;
#pragma unroll
    for (int i = 0; i < 25; i++) {
        loc[i] = run;
        int idx = base + i;
        run += (idx < N) ? deg[idx] : 0;
    }
    int inc = run;
#pragma unroll
    for (int s = 1; s < 64; s <<= 1) {
        int v = __shfl_up(inc, s, 64);
        if (lane >= s) inc += v;
    }
    if (lane == 63) wsum[wv] = inc;
    __syncthreads();
    if (t < 16) {
        int v = wsum[t];
#pragma unroll
        for (int s = 1; s < 16; s <<= 1) {
            int u = __shfl_up(v, s, 64);
            if (t >= s) v += u;
        }
        wsum[t] = v;
    }
    __syncthreads();
    int pbase = inc - run + (wv ? wsum[wv - 1] : 0);
#pragma unroll
    for (int i = 0; i < 25; i++) {
        int idx = base + i;
        if (idx <= N) rowptr[idx] = pbase + loc[i];
    }
}

// CSR scatter + edge-MLP: PK[l][pos] = {src_as_float, t0, t1, t2}
__global__ void scatter_kernel(const int* __restrict__ ei, const float* __restrict__ ea,
                               const float* __restrict__ w1, const float* __restrict__ b1,
                               const int* __restrict__ rowptr, int* __restrict__ cnt,
                               float* __restrict__ PK) {
    int e = blockIdx.x * 256 + threadIdx.x;
    if (e >= E) return;
    int s = ei[e], d = ei[E + e];
    int pos = rowptr[d] + atomicAdd(&cnt[d], 1);
    float a[10];
#pragma unroll
    for (int j = 0; j < 10; j++) a[j] = ea[e * 10 + j];
#pragma unroll
    for (int l = 0; l < 3; l++) {
        float tk[3];
#pragma unroll
        for (int k = 0; k < 3; k++) {
            float acc = b1[l * 3 + k];
#pragma unroll
            for (int j = 0; j < 10; j++) acc += a[j] * w1[l * 30 + j * 3 + k];
            tk[k] = fmaxf(acc, 0.f);
        }
        float4 rec = make_float4(__int_as_float(s), tk[0], tk[1], tk[2]);
        *reinterpret_cast<float4*>(PK + ((size_t)l * E + pos) * 4) = rec;
    }
}

// shared GEMM phase: hs[BPN][52] -> U[n][o*4+k] (t<196) and Rt[n][o]=h@rw+cb (t in [196,245))
__device__ __forceinline__ void gemm_phase(const float (*hs)[52], int base, int nv,
                                           const float* __restrict__ w2,
                                           const float* __restrict__ b2,
                                           const float* __restrict__ rw,
                                           const float* __restrict__ cb,
                                           float* __restrict__ U, float* __restrict__ Rt,
                                           int t) {
    if (t >= 245) return;
    int k = t / C, o = t % C;
    const float* Wp = (k < 3 ? w2 + k * (C * C) : (k == 3 ? b2 : rw)) + o;
    float bias = (k == 4) ? cb[o] : 0.f;
    float w[52];
#pragma unroll
    for (int i = 0; i < C; i++) w[i] = Wp[i * C];
    w[49] = w[50] = w[51] = 0.f;
#pragma unroll 2
    for (int n = 0; n < nv; n++) {
        float acc = bias;
#pragma unroll
        for (int i4 = 0; i4 < 13; i4++) {
            float4 hv = *reinterpret_cast<const float4*>(&hs[n][i4 * 4]);
            acc += hv.x * w[i4 * 4] + hv.y * w[i4 * 4 + 1] + hv.z * w[i4 * 4 + 2] +
                   hv.w * w[i4 * 4 + 3];
        }
        if (k < 4) U[(size_t)(base + n) * C2 + o * 4 + k] = acc;
        else Rt[(size_t)(base + n) * C + o] = acc;
    }
}

// fused: h = leaky(x@lin_w+lin_b) -> out(JK init) + hs; then U0, Rt0
__global__ __launch_bounds__(256) void h2u0_kernel(
    const float* __restrict__ x, const float* __restrict__ lw, const float* __restrict__ lb,
    const float* __restrict__ w2, const float* __restrict__ b2, const float* __restrict__ rw,
    const float* __restrict__ cb, float* __restrict__ out, float* __restrict__ U,
    float* __restrict__ Rt) {
    __shared__ float xs[BPN][56];
    __shared__ float hs[BPN][52];
    int t = threadIdx.x, base = blockIdx.x * BPN;
    int nv = min(BPN, N - base);
    for (int e = t; e < nv * 56; e += 256) xs[e / 56][e % 56] = x[(size_t)base * 56 + e];
    for (int j = t; j < BPN * 3; j += 256) hs[j / 3][C + (j % 3)] = 0.f;
    __syncthreads();
    int r = t >> 6, c = t & 63;
    if (c < C) {
        float w[56];
#pragma unroll
        for (int i = 0; i < 56; i++) w[i] = lw[i * C + c];
        float bias = lb[c];
        for (int n = r; n < nv; n += 4) {
            float acc = bias;
#pragma unroll
            for (int i4 = 0; i4 < 14; i4++) {
                float4 hv = *reinterpret_cast<const float4*>(&xs[n][i4 * 4]);
                acc += hv.x * w[i4 * 4] + hv.y * w[i4 * 4 + 1] + hv.z * w[i4 * 4 + 2] +
                       hv.w * w[i4 * 4 + 3];
            }
            acc = leaky(acc);
            out[(size_t)(base + n) * C + c] = acc;
            hs[n][c] = acc;
        }
    }
    __syncthreads();
    gemm_phase(hs, base, nv, w2, b2, rw, cb, U, Rt, t);
}

// BN finalize (from raw replicated S/Q) + apply -> JK out + hs; then U, Rt
__global__ __launch_bounds__(256) void uni_kernel(
    const float* __restrict__ in, const float* __restrict__ stRaw,
    const float* __restrict__ gm, const float* __restrict__ bt,
    const float* __restrict__ w2, const float* __restrict__ b2,
    const float* __restrict__ rw, const float* __restrict__ cb,
    float* __restrict__ out, float* __restrict__ U, float* __restrict__ Rt) {
    __shared__ float hs[BPN][52];
    __shared__ float scl[64], sft[64];
    int t = threadIdx.x, base = blockIdx.x * BPN;
    int nv = min(BPN, N - base);
    if (t < C) {
        float S = 0.f, Q = 0.f;
#pragma unroll
        for (int r = 0; r < NREP; r++) {
            S += stRaw[r * 128 + t];
            Q += stRaw[r * 128 + 64 + t];
        }
        float mu = S * (1.0f / N);
        float var = Q * (1.0f / N) - mu * mu;
        float sc = rsqrtf(var + 1e-5f) * gm[t];
        scl[t] = sc;
        sft[t] = bt[t] - mu * sc;
    }
    for (int j = t; j < BPN * 3; j += 256) hs[j / 3][C + j % 3] = 0.f;
    __syncthreads();
    for (int e = t; e < nv * C; e += 256) {
        int n = e / C, i = e % C;
        float v = in[(size_t)base * C + e];
        v = leaky(v * scl[i] + sft[i]);
        out[(size_t)base * C + e] += v;
        hs[n][i] = v;
    }
    __syncthreads();
    gemm_phase(hs, base, nv, w2, b2, rw, cb, U, Rt, t);
}

// CSR gather (4-edge branchless quads) + Rt add => pre; per-block stats -> replicated slots
__global__ __launch_bounds__(256) void gathpre_kernel(
    const int* __restrict__ rowptr, const float* __restrict__ PK, const float* __restrict__ U,
    const float* __restrict__ Rt, float* __restrict__ pre, float* __restrict__ st) {
    __shared__ float red[8][64];
    int t = threadIdx.x, wv = t >> 6, c = t & 63;
    int n0 = blockIdx.x * NPB + wv * GK;
    float s = 0.f, q = 0.f;
    int nend = min(n0 + GK, N);
    const float4* PK4 = reinterpret_cast<const float4*>(PK);
    for (int n = n0; n < nend; n++) {
        int nu = RFL(n);
        int j0 = RFL(rowptr[nu]);
        int j1 = RFL(rowptr[nu + 1]);
        if (c < C) {
            float rr = Rt[(size_t)nu * C + c];
            float a0 = 0.f, a1 = 0.f, a2 = 0.f, a3 = 0.f;
            int jc = max(j1 - 1, j0);  // clamp target (deg=0 safe)
            int j = j0;
            do {
#define EDGE_TERM(K, AK)                                                          \
                {                                                                 \
                    int jj = min(j + K, jc);                                      \
                    float4 m = PK4[jj];                                           \
                    int sidx = RFL(__float_as_int(m.x));                          \
                    sidx = min(max(sidx, 0), N - 1);                              \
                    float4 u = *reinterpret_cast<const float4*>(                  \
                        U + (size_t)sidx * C2 + c * 4);                           \
                    float sc = (j + K < j1) ? 1.f : 0.f;                          \
                    AK += sc * (m.y * u.x + m.z * u.y + m.w * u.z + u.w);         \
                }
                EDGE_TERM(0, a0)
                EDGE_TERM(1, a1)
                EDGE_TERM(2, a2)
                EDGE_TERM(3, a3)
#undef EDGE_TERM
                j += 4;
            } while (j < j1);
            float inv = 1.0f / fmaxf((float)(j1 - j0), 1.0f);
            float acc = (a0 + a1 + a2 + a3) * inv + rr;
            pre[(size_t)nu * C + c] = acc;
            s += acc;
            q += acc * acc;
        }
    }
    red[wv][c] = s;
    red[4 + wv][c] = q;
    __syncthreads();
    if (t < C) {
        float* slot = st + (blockIdx.x & (NREP - 1)) * 128;
        float S = red[0][t] + red[1][t] + red[2][t] + red[3][t];
        float Q = red[4][t] + red[5][t] + red[6][t] + red[7][t];
        atomicAdd(&slot[t], S);
        atomicAdd(&slot[64 + t], Q);
    }
}

// last layer: out += leaky(pre*sc+sh); BN finalize per block from raw stats
__global__ __launch_bounds__(256) void fnorm_kernel(const float* __restrict__ pre,
                                                    const float* __restrict__ stRaw,
                                                    const float* __restrict__ gm,
                                                    const float* __restrict__ bt,
                                                    float* __restrict__ out) {
    __shared__ float scl[64], sft[64];
    int t = threadIdx.x;
    if (t < C) {
        float S = 0.f, Q = 0.f;
#pragma unroll
        for (int r = 0; r < NREP; r++) {
            S += stRaw[r * 128 + t];
            Q += stRaw[r * 128 + 64 + t];
        }
        float mu = S * (1.0f / N);
        float var = Q * (1.0f / N) - mu * mu;
        float sc = rsqrtf(var + 1e-5f) * gm[t];
        scl[t] = sc;
        sft[t] = bt[t] - mu * sc;
    }
    __syncthreads();
    for (int idx = blockIdx.x * 256 + t; idx < N * C; idx += gridDim.x * 256) {
        int c = idx % C;
        out[idx] += leaky(pre[idx] * scl[c] + sft[c]);
    }
}

extern "C" void kernel_launch(void* const* d_in, const int* in_sizes, int n_in,
                              void* d_out, int out_size, void* d_ws, size_t ws_size,
                              hipStream_t stream) {
    const float* x  = (const float*)d_in[0];
    const int* ei   = (const int*)d_in[1];
    const float* ea = (const float*)d_in[2];
    const float* lw = (const float*)d_in[3];
    const float* lb = (const float*)d_in[4];
    const float* w1 = (const float*)d_in[5];
    const float* b1 = (const float*)d_in[6];
    const float* w2 = (const float*)d_in[7];
    const float* b2 = (const float*)d_in[8];
    const float* rw = (const float*)d_in[9];
    const float* cb = (const float*)d_in[10];
    const float* gm = (const float*)d_in[11];
    const float* bt = (const float*)d_in[12];
    float* out = (float*)d_out;

    float* ws     = (float*)d_ws;
    int*   deg    = (int*)ws;                 // N
    int*   cnt    = deg + N;                  // N
    float* st     = (float*)(cnt + N);        // 3*1024 (layer l at st+1024*l, NREP slots of 128)
    int*   rowptr = (int*)(st + 3 * 1024);    // N+1
    float* PK     = (float*)(rowptr + N + 1); // 3*E*4
    float* agg    = PK + (size_t)12 * E;      // N*C (pre)
    float* Rt     = agg + (size_t)N * C;      // N*C
    float* U      = Rt + (size_t)N * C;       // N*C2

    hipMemsetAsync(deg, 0, (size_t)(2 * N + 3 * 1024) * sizeof(int), stream);
    deg_kernel<<<(E + 255) / 256, 256, 0, stream>>>(ei, deg);
    scan_kernel<<<1, 1024, 0, stream>>>(deg, rowptr);
    scatter_kernel<<<(E + 255) / 256, 256, 0, stream>>>(ei, ea, w1, b1, rowptr, cnt, PK);
    h2u0_kernel<<<(N + BPN - 1) / BPN, 256, 0, stream>>>(x, lw, lb, w2, b2, rw, cb, out, U, Rt);

    const int GPB = (N + NPB - 1) / NPB;
    for (int l = 0; l < 3; l++) {
        if (l > 0) {
            uni_kernel<<<(N + BPN - 1) / BPN, 256, 0, stream>>>(
                agg, st + (size_t)(l - 1) * 1024, gm + (l - 1) * C, bt + (l - 1) * C,
                w2 + (size_t)l * 3 * C * C, b2 + (size_t)l * C * C,
                rw + (size_t)l * C * C, cb + l * C, out, U, Rt);
        }
        gathpre_kernel<<<GPB, 256, 0, stream>>>(
            rowptr, PK + (size_t)l * E * 4, U, Rt, agg, st + (size_t)l * 1024);
    }
    fnorm_kernel<<<512, 256, 0, stream>>>(agg, st + 2 * 1024, gm + 2 * C, bt + 2 * C, out);
}